// Round 19
// baseline (231.363 us; speedup 1.0000x reference)
//
#include <hip/hip_runtime.h>
#include <stdint.h>

#define DEVINL __device__ __forceinline__

typedef __bf16 bf16x8 __attribute__((ext_vector_type(8)));
typedef float f32x4 __attribute__((ext_vector_type(4)));
typedef float f32x16 __attribute__((ext_vector_type(16)));
typedef uint32_t u32x4 __attribute__((ext_vector_type(4)));

DEVINL uint16_t f2bf(float f) {
    uint32_t u = __builtin_bit_cast(uint32_t, f);
    uint32_t r = (u + 0x7FFFu + ((u >> 16) & 1u)) >> 16;
    return (uint16_t)r;
}

DEVINL bf16x8 ld8(const uint16_t* p) {
    u32x4 v = *(const u32x4*)p;
    return __builtin_bit_cast(bf16x8, v);
}

DEVINL void gload16(const void* g, void* l) {
    __builtin_amdgcn_global_load_lds(
        (const __attribute__((address_space(1))) uint32_t*)g,
        (__attribute__((address_space(3))) uint32_t*)l, 16, 0, 0);
}

DEVINL uint32_t cvtpk(float lo, float hi) {
    uint32_t r;
    asm("v_cvt_pk_bf16_f32 %0, %1, %2" : "=v"(r) : "v"(lo), "v"(hi));
    return r;
}

DEVINL float exp2_fast(float x) {
    float r;
    asm("v_exp_f32 %0, %1" : "=v"(r) : "v"(x));
    return r;
}

// ---------------- fused prep: cvt x -> bf16 ; transpose+cvt Wqkv, Wproj ----------------
DEVINL void transW_body(const float* __restrict__ W, uint16_t* __restrict__ WT,
                        int Nn, int n0, int k0, int tid, uint16_t* t) {
#pragma unroll
    for (int i = 0; i < 4; ++i) {
        int c = tid + i * 256;              // 1024 float4 chunks
        int kr = c >> 4, nc = c & 15;
        float4 v = *(const float4*)(W + (size_t)(k0 + kr) * Nn + n0 + nc * 4);
        t[(nc * 4 + 0) * 65 + kr] = f2bf(v.x);
        t[(nc * 4 + 1) * 65 + kr] = f2bf(v.y);
        t[(nc * 4 + 2) * 65 + kr] = f2bf(v.z);
        t[(nc * 4 + 3) * 65 + kr] = f2bf(v.w);
    }
    __syncthreads();
#pragma unroll
    for (int i = 0; i < 2; ++i) {
        int c = tid + i * 256;              // 512 chunks of 8 bf16
        int nr = c >> 3, kc = c & 7;
        union { uint16_t u[8]; u32x4 v; } o;
#pragma unroll
        for (int j = 0; j < 8; ++j) o.u[j] = t[nr * 65 + kc * 8 + j];
        *(u32x4*)(WT + (size_t)(n0 + nr) * 1024 + k0 + kc * 8) = o.v;
    }
}

__global__ void k_prep(const float* __restrict__ x, uint16_t* __restrict__ xb,
                       const float* __restrict__ Wqkv, uint16_t* __restrict__ wqkvT,
                       const float* __restrict__ Wproj, uint16_t* __restrict__ wprojT) {
    __shared__ uint16_t t[64 * 65];
    int bid = blockIdx.x;
    int tid = threadIdx.x;
    if (bid < 4096) {
        int i = bid * 256 + tid;            // 1048576 chunks of 8 floats
        const float4* src = (const float4*)x + (size_t)i * 2;
        float4 a = src[0], b = src[1];
        union { uint16_t u[8]; u32x4 v; } o;
        o.u[0] = f2bf(a.x); o.u[1] = f2bf(a.y); o.u[2] = f2bf(a.z); o.u[3] = f2bf(a.w);
        o.u[4] = f2bf(b.x); o.u[5] = f2bf(b.y); o.u[6] = f2bf(b.z); o.u[7] = f2bf(b.w);
        ((u32x4*)xb)[i] = o.v;
    } else if (bid < 4864) {
        int idx = bid - 4096;               // 48 x 16 tiles
        transW_body(Wqkv, wqkvT, 3072, (idx % 48) * 64, (idx / 48) * 64, tid, t);
    } else {
        int idx = bid - 4864;               // 16 x 16 tiles
        transW_body(Wproj, wprojT, 1024, (idx % 16) * 64, (idx / 16) * 64, tid, t);
    }
}

// ---------------- GEMM: [8192][1024] x BT[Nd][1024], BM=256 BN=128 BK=64 ----------------
// 8 waves (512 thr), double-buffered dynamic LDS 96KB. Stagger-by-one
// pipeline with ONE order-invariant vmcnt(0)+barrier per K-step; stage/compute
// sub-phase interleave (R17).
// MODE 0: QKV. nt 0..7 q (scaled), 8..15 k, 16..23 v (LDS-transposed to v^T).
// MODE 1: proj -> out f32 + bias.
template <int MODE>
__global__ __launch_bounds__(512) void k_gemm(
    const uint16_t* __restrict__ A, const uint16_t* __restrict__ BT,
    const float* __restrict__ bias,
    uint16_t* __restrict__ qo, uint16_t* __restrict__ ko, uint16_t* __restrict__ vo,
    float* __restrict__ out) {
    extern __shared__ uint16_t lds[];
    int tid = threadIdx.x;
    int w = tid >> 6, l = tid & 63;
    int l15 = l & 15, l4 = l >> 4;
    int wr = w >> 2, wc = w & 3;
    int bid = blockIdx.x;
    int mt = (bid & 7) * 4 + ((bid >> 3) & 3);   // XCD-chunked M
    int nt = bid >> 5;                            // B-panel index
    int m0 = mt * 256, n0 = nt * 128;

    int r0 = tid >> 3, sl0 = tid & 7;
    int kc = sl0 ^ (r0 & 7);
    const uint16_t* pA = A + (size_t)(m0 + r0) * 1024 + kc * 8;
    const uint16_t* pB = BT + (size_t)(n0 + r0) * 1024 + kc * 8;
    int wofs = w * 512;

    f32x4 acc[8][2] = {};

    auto stageA = [&](int ks, int abA) {
#pragma unroll
        for (int q = 0; q < 4; ++q)
            gload16(pA + q * 65536 + ks * 64, lds + abA + q * 4096 + wofs);
    };
    auto stageB = [&](int ks, int abB) {
#pragma unroll
        for (int li = 0; li < 2; ++li)
            gload16(pB + li * 65536 + ks * 64, lds + abB + li * 4096 + wofs);
    };

    auto computeHalf = [&](int abA, int abB, int kk) {
        const uint16_t* Ah = lds + abA + wr * 8192;
        const uint16_t* Bb = lds + abB;
        int ch = ((kk * 4 + l4) ^ (l15 & 7)) * 8;
        bf16x8 af[8], bf[2];
#pragma unroll
        for (int fi = 0; fi < 8; ++fi)
            af[fi] = ld8(Ah + (fi * 16 + l15) * 64 + ch);
#pragma unroll
        for (int fj = 0; fj < 2; ++fj)
            bf[fj] = ld8(Bb + (wc * 32 + fj * 16 + l15) * 64 + ch);
        __builtin_amdgcn_s_setprio(1);
#pragma unroll
        for (int fi = 0; fi < 8; ++fi)
#pragma unroll
            for (int fj = 0; fj < 2; ++fj)
                acc[fi][fj] = __builtin_amdgcn_mfma_f32_16x16x32_bf16(
                    af[fi], bf[fj], acc[fi][fj], 0, 0, 0);
        __builtin_amdgcn_s_setprio(0);
    };

    auto step = [&](int s, int abA, int abB, int abAn, int abBn) {
        bool pf = (s + 1 < 16);
        if (pf) stageA(s + 1, abAn);
        computeHalf(abA, abB, 0);
        if (pf) stageB(s + 1, abBn);
        computeHalf(abA, abB, 1);
        asm volatile("s_waitcnt vmcnt(0)\n\ts_barrier" ::: "memory");
    };

    stageA(0, 0); stageB(0, 32768);
    asm volatile("s_waitcnt vmcnt(0)\n\ts_barrier" ::: "memory");
    for (int s = 0; s < 16; s += 2) {
        step(s,     0,     32768, 16384, 40960);
        step(s + 1, 16384, 40960, 0,     32768);
    }

    if constexpr (MODE == 0) {
        int b = m0 >> 11, nbase = m0 & 2047;
        if (n0 >= 2048) {
#pragma unroll
            for (int fi = 0; fi < 8; ++fi)
#pragma unroll
                for (int fj = 0; fj < 2; ++fj) {
                    int dl = wc * 32 + fj * 16 + l15;
                    int ml = wr * 128 + fi * 16 + l4 * 4;
                    union { uint16_t u[4]; uint2 v2; } pk;
#pragma unroll
                    for (int r = 0; r < 4; ++r) pk.u[r] = f2bf(acc[fi][fj][r]);
                    *(uint2*)&lds[dl * 264 + ml] = pk.v2;
                }
        __syncthreads();
#pragma unroll
            for (int it = 0; it < 8; ++it) {
                int idx = it * 512 + tid;
                int row = idx >> 5, col = (idx & 31) * 8;
                u32x4 val = *(u32x4*)&lds[row * 264 + col];
                int dv = (n0 - 2048) + row;
                int h = dv >> 6, dh = dv & 63;
                *(u32x4*)(vo + ((size_t)(b * 16 + h) * 64 + dh) * 2048 + nbase + col) = val;
            }
        } else {
            float sc = (n0 < 1024) ? 0.18033688011112042f : 1.0f;
            uint16_t* dst0 = (n0 < 1024) ? qo : ko;
#pragma unroll
            for (int fi = 0; fi < 8; ++fi)
#pragma unroll
                for (int fj = 0; fj < 2; ++fj) {
                    int d = n0 + wc * 32 + fj * 16 + l15;
                    int h = (d >> 6) & 15, dh = d & 63;
#pragma unroll
                    for (int r = 0; r < 4; ++r) {
                        int n = nbase + wr * 128 + fi * 16 + l4 * 4 + r;
                        dst0[((size_t)(b * 16 + h) * 2048 + n) * 64 + dh] = f2bf(acc[fi][fj][r] * sc);
                    }
                }
        }
    } else {
#pragma unroll
        for (int fj = 0; fj < 2; ++fj) {
            int d = n0 + wc * 32 + fj * 16 + l15;
            float bv = bias[d];
#pragma unroll
            for (int fi = 0; fi < 8; ++fi)
#pragma unroll
                for (int r = 0; r < 4; ++r) {
                    int m = m0 + wr * 128 + fi * 16 + l4 * 4 + r;
                    out[(size_t)m * 1024 + d] = acc[fi][fj][r] + bv;
                }
        }
    }
}

// ---------------- flash attention (no-max softmax, exp2 domain, KVBLK=128) ----------------
// R19: R18's proven KVBLK=128 body with SINGLE-BUFFERED V -> LDS 64->48KB ->
// 3 blocks/CU (12 waves/CU, +50% TLP). Wait structure stays in the proven
// class:
//   prologue: stageK(0->buf0); stageV(0)            [K-group before V-group]
//   body t: vmcnt(4)+bar [K(t) = oldest 4 done; V(t) 4 in flight]
//           -> if(t<15) stageK(t+1 -> other buf)    [WAR ok: QK(t-1) readers
//              passed the previous body's vmcnt(0) barrier]
//           -> QK(t) 4 j-groups + exp
//           -> vmcnt(0)+bar [order-invariant: V(t) ready; K(t+1) had the
//              whole QK phase (~2000cyc) of cover so the drain is ~free]
//           -> PV(t)
//           -> if(t<15) { s_barrier [all waves' PV LDS reads complete, since
//              their PV MFMAs issued]; stageV(t+1) }   [K before V order kept
//              by the intervening asm memory clobbers]
__global__ __launch_bounds__(256) void k_attn(
    const uint16_t* __restrict__ q, const uint16_t* __restrict__ kk_,
    const uint16_t* __restrict__ vt, uint16_t* __restrict__ o) {
    __shared__ uint16_t k_lds[2][128 * 64];
    __shared__ uint16_t v_lds[64 * 128];
    int tid = threadIdx.x;
    int w = tid >> 6, l = tid & 63;
    int l31 = l & 31, g = l >> 5;
    int bid = blockIdx.x;
    int slot = bid >> 3;
    int bh = (bid & 7) * 8 + (slot >> 4);
    int qt = slot & 15;
    int qrow = qt * 128 + w * 32 + l31;
    const uint16_t* qb = q + ((size_t)bh * 2048 + qrow) * 64;
    const uint16_t* kbase = kk_ + (size_t)bh * 2048 * 64;
    const uint16_t* vbase = vt + (size_t)bh * 64 * 2048;

    bf16x8 qf[4];
#pragma unroll
    for (int kv = 0; kv < 4; ++kv) qf[kv] = ld8(qb + kv * 16 + g * 8);

    // K staging: thread covers chunks c0+{0,64,128,192} (rows rrK+{0,8,16,24},
    // same slot; (rrK+8i)&7 == rrK&7 so one swizzled base + imm offsets works)
    int c0 = w * 256 + l;
    int rrK = c0 >> 3, slK = c0 & 7;
    int kcK = slK ^ (rrK & 7);
    const uint16_t* kp = kbase + (size_t)rrK * 64 + kcK * 8;
    // V^T staging: load i covers row rv0+4i, slot l&15 (XOR low-3 swizzle)
    int rv0 = w * 16 + (l >> 4);
    int sv = l & 15;
    const uint16_t* vpp0 = vbase + (size_t)(rv0 + 0)  * 2048 + (sv ^ ((rv0 + 0)  & 7)) * 8;
    const uint16_t* vpp1 = vbase + (size_t)(rv0 + 4)  * 2048 + (sv ^ ((rv0 + 4)  & 7)) * 8;
    const uint16_t* vpp2 = vbase + (size_t)(rv0 + 8)  * 2048 + (sv ^ ((rv0 + 8)  & 7)) * 8;
    const uint16_t* vpp3 = vbase + (size_t)(rv0 + 12) * 2048 + (sv ^ ((rv0 + 12) & 7)) * 8;
    uint16_t* kd0 = k_lds[0] + w * 2048;
    uint16_t* kd1 = k_lds[1] + w * 2048;
    uint16_t* vd  = v_lds + w * 2048;

    f32x16 oa[2] = {};
    float lsum = 0.f;

    auto stageK = [&](uint16_t* kd) {
        gload16(kp,        kd);        gload16(kp + 512,  kd + 512);
        gload16(kp + 1024, kd + 1024); gload16(kp + 1536, kd + 1536);
        kp += 8192;
    };
    auto stageV = [&]() {
        gload16(vpp0, vd);        gload16(vpp1, vd + 512);
        gload16(vpp2, vd + 1024); gload16(vpp3, vd + 1536);
        vpp0 += 128; vpp1 += 128; vpp2 += 128; vpp3 += 128;
    };

    stageK(kd0);   // K(0) -> buf0 (4 outstanding)
    stageV();      // V(0)          (8 outstanding)

    auto body = [&](int t, const uint16_t* kb, uint16_t* kdn) {
        // K(t) ready (oldest 4); V(t)'s 4 still in flight
        asm volatile("s_waitcnt vmcnt(4)\n\ts_barrier" ::: "memory");
        if (t < 15) stageK(kdn);   // K(t+1) -> other buf

        // S^T = K * Q^T, P = exp2(S) in-register (4 x 32-key groups)
        bf16x8 pfrag[8];
#pragma unroll
        for (int j = 0; j < 4; ++j) {
            int key = j * 32 + l31;
            f32x16 stj = {};
            __builtin_amdgcn_s_setprio(1);
#pragma unroll
            for (int kv = 0; kv < 4; ++kv) {
                bf16x8 kf = ld8(kb + key * 64 + ((2 * kv + g) ^ (key & 7)) * 8);
                stj = __builtin_amdgcn_mfma_f32_32x32x16_bf16(kf, qf[kv], stj, 0, 0, 0);
            }
            __builtin_amdgcn_s_setprio(0);
#pragma unroll
            for (int h = 0; h < 2; ++h) {
                float e[8];
#pragma unroll
                for (int jj = 0; jj < 8; ++jj) e[jj] = exp2_fast(stj[h * 8 + jj]);
                lsum += ((e[0] + e[1]) + (e[2] + e[3])) + ((e[4] + e[5]) + (e[6] + e[7]));
                uint32_t a0 = cvtpk(e[0], e[1]), a1 = cvtpk(e[2], e[3]);
                uint32_t b0 = cvtpk(e[4], e[5]), b1 = cvtpk(e[6], e[7]);
                auto r0 = __builtin_amdgcn_permlane32_swap(a0, b0, false, false);
                auto r1 = __builtin_amdgcn_permlane32_swap(a1, b1, false, false);
                u32x4 f;
                f[0] = r0[0]; f[1] = r1[0]; f[2] = r0[1]; f[3] = r1[1];
                pfrag[j * 2 + h] = __builtin_bit_cast(bf16x8, f);
            }
        }

        // V(t) ready (order-invariant full drain; K(t+1) had QK-phase cover)
        asm volatile("s_waitcnt vmcnt(0)\n\ts_barrier" ::: "memory");

        // O^T += V^T * P^T  (8 x 16-key slots)
        __builtin_amdgcn_s_setprio(1);
#pragma unroll
        for (int kv = 0; kv < 8; ++kv) {
#pragma unroll
            for (int dt = 0; dt < 2; ++dt) {
                int dh = dt * 32 + l31;
                bf16x8 vf = ld8(v_lds + dh * 128 + ((2 * kv + g) ^ (dh & 7)) * 8);
                oa[dt] = __builtin_amdgcn_mfma_f32_32x32x16_bf16(vf, pfrag[kv], oa[dt], 0, 0, 0);
            }
        }
        __builtin_amdgcn_s_setprio(0);

        if (t < 15) {
            // all waves' PV LDS reads complete (their MFMAs issued) -> WAR safe
            asm volatile("s_barrier" ::: "memory");
            stageV();   // V(t+1)
        }
    };

    for (int kt = 0; kt < 16; kt += 2) {
        body(kt,     k_lds[0], kd1);
        body(kt + 1, k_lds[1], kd0);
    }

    float ltot = lsum + __shfl_xor(lsum, 32, 64);
    float inv = 1.0f / ltot;
    int b = bh >> 4, h = bh & 15;
    uint16_t* ob = o + ((size_t)(b * 2048 + qrow)) * 1024 + h * 64;
#pragma unroll
    for (int dt = 0; dt < 2; ++dt)
#pragma unroll
        for (int rq = 0; rq < 4; ++rq) {
            union { uint16_t u[4]; uint2 v; } pk;
#pragma unroll
            for (int rr = 0; rr < 4; ++rr) pk.u[rr] = f2bf(oa[dt][rq * 4 + rr] * inv);
            int dh0 = dt * 32 + rq * 8 + g * 4;
            *(uint2*)(ob + dh0) = pk.v;
        }
}

extern "C" void kernel_launch(void* const* d_in, const int* in_sizes, int n_in,
                              void* d_out, int out_size, void* d_ws, size_t ws_size,
                              hipStream_t stream) {
    const float* x     = (const float*)d_in[0];
    // d_in[1] = xpos : unused by the reference
    const float* Wqkv  = (const float*)d_in[2];
    const float* Wproj = (const float*)d_in[3];
    const float* bproj = (const float*)d_in[4];
    float* out = (float*)d_out;

    char* ws = (char*)d_ws;
    uint16_t* xb     = (uint16_t*)(ws);                         // 16.78 MB
    uint16_t* wqkvT  = (uint16_t*)(ws + 16777216);              //  6.29 MB
    uint16_t* wprojT = (uint16_t*)(ws + 23068672);              //  2.10 MB
    uint16_t* qws    = (uint16_t*)(ws + 25165824);              // 16.78 MB
    uint16_t* kws    = (uint16_t*)(ws + 41943040);              // 16.78 MB
    uint16_t* vT     = (uint16_t*)(ws + 58720256);              // 16.78 MB (total ~75.5 MB)
    uint16_t* attnout = xb;  // xb is dead after QKV GEMM

    k_prep<<<dim3(5120), dim3(256), 0, stream>>>(x, xb, Wqkv, wqkvT, Wproj, wprojT);
    k_gemm<0><<<dim3(768), dim3(512), 98304, stream>>>(xb, wqkvT, nullptr, qws, kws, vT, nullptr);
    k_attn<<<dim3(1024), dim3(256), 0, stream>>>(qws, kws, vT, attnout);
    k_gemm<1><<<dim3(256), dim3(512), 98304, stream>>>(attnout, wprojT, bproj, nullptr, nullptr, nullptr, out);
}

// Round 20
// 189.020 us; speedup vs baseline: 1.2240x; 1.2240x over previous
//
#include <hip/hip_runtime.h>
#include <stdint.h>

#define DEVINL __device__ __forceinline__

typedef __bf16 bf16x8 __attribute__((ext_vector_type(8)));
typedef float f32x4 __attribute__((ext_vector_type(4)));
typedef float f32x16 __attribute__((ext_vector_type(16)));
typedef uint32_t u32x4 __attribute__((ext_vector_type(4)));

DEVINL uint16_t f2bf(float f) {
    uint32_t u = __builtin_bit_cast(uint32_t, f);
    uint32_t r = (u + 0x7FFFu + ((u >> 16) & 1u)) >> 16;
    return (uint16_t)r;
}

DEVINL bf16x8 ld8(const uint16_t* p) {
    u32x4 v = *(const u32x4*)p;
    return __builtin_bit_cast(bf16x8, v);
}

DEVINL void gload16(const void* g, void* l) {
    __builtin_amdgcn_global_load_lds(
        (const __attribute__((address_space(1))) uint32_t*)g,
        (__attribute__((address_space(3))) uint32_t*)l, 16, 0, 0);
}

DEVINL uint32_t cvtpk(float lo, float hi) {
    uint32_t r;
    asm("v_cvt_pk_bf16_f32 %0, %1, %2" : "=v"(r) : "v"(lo), "v"(hi));
    return r;
}

DEVINL float exp2_fast(float x) {
    float r;
    asm("v_exp_f32 %0, %1" : "=v"(r) : "v"(x));
    return r;
}

// ---------------- fused prep: cvt x -> bf16 ; transpose+cvt Wqkv, Wproj ----------------
DEVINL void transW_body(const float* __restrict__ W, uint16_t* __restrict__ WT,
                        int Nn, int n0, int k0, int tid, uint16_t* t) {
#pragma unroll
    for (int i = 0; i < 4; ++i) {
        int c = tid + i * 256;              // 1024 float4 chunks
        int kr = c >> 4, nc = c & 15;
        float4 v = *(const float4*)(W + (size_t)(k0 + kr) * Nn + n0 + nc * 4);
        t[(nc * 4 + 0) * 65 + kr] = f2bf(v.x);
        t[(nc * 4 + 1) * 65 + kr] = f2bf(v.y);
        t[(nc * 4 + 2) * 65 + kr] = f2bf(v.z);
        t[(nc * 4 + 3) * 65 + kr] = f2bf(v.w);
    }
    __syncthreads();
#pragma unroll
    for (int i = 0; i < 2; ++i) {
        int c = tid + i * 256;              // 512 chunks of 8 bf16
        int nr = c >> 3, kc = c & 7;
        union { uint16_t u[8]; u32x4 v; } o;
#pragma unroll
        for (int j = 0; j < 8; ++j) o.u[j] = t[nr * 65 + kc * 8 + j];
        *(u32x4*)(WT + (size_t)(n0 + nr) * 1024 + k0 + kc * 8) = o.v;
    }
}

__global__ void k_prep(const float* __restrict__ x, uint16_t* __restrict__ xb,
                       const float* __restrict__ Wqkv, uint16_t* __restrict__ wqkvT,
                       const float* __restrict__ Wproj, uint16_t* __restrict__ wprojT) {
    __shared__ uint16_t t[64 * 65];
    int bid = blockIdx.x;
    int tid = threadIdx.x;
    if (bid < 4096) {
        int i = bid * 256 + tid;            // 1048576 chunks of 8 floats
        const float4* src = (const float4*)x + (size_t)i * 2;
        float4 a = src[0], b = src[1];
        union { uint16_t u[8]; u32x4 v; } o;
        o.u[0] = f2bf(a.x); o.u[1] = f2bf(a.y); o.u[2] = f2bf(a.z); o.u[3] = f2bf(a.w);
        o.u[4] = f2bf(b.x); o.u[5] = f2bf(b.y); o.u[6] = f2bf(b.z); o.u[7] = f2bf(b.w);
        ((u32x4*)xb)[i] = o.v;
    } else if (bid < 4864) {
        int idx = bid - 4096;               // 48 x 16 tiles
        transW_body(Wqkv, wqkvT, 3072, (idx % 48) * 64, (idx / 48) * 64, tid, t);
    } else {
        int idx = bid - 4864;               // 16 x 16 tiles
        transW_body(Wproj, wprojT, 1024, (idx % 16) * 64, (idx / 16) * 64, tid, t);
    }
}

// ---------------- GEMM: [8192][1024] x BT[Nd][1024], BM=256 BN=128 BK=64 ----------------
// 8 waves (512 thr), double-buffered dynamic LDS 96KB. Stagger-by-one
// pipeline with ONE order-invariant vmcnt(0)+barrier per K-step; stage/compute
// sub-phase interleave (R17, +1.5us).
// MODE 0: QKV. nt 0..7 q (scaled), 8..15 k, 16..23 v (LDS-transposed to v^T).
// MODE 1: proj -> out f32 + bias.
template <int MODE>
__global__ __launch_bounds__(512) void k_gemm(
    const uint16_t* __restrict__ A, const uint16_t* __restrict__ BT,
    const float* __restrict__ bias,
    uint16_t* __restrict__ qo, uint16_t* __restrict__ ko, uint16_t* __restrict__ vo,
    float* __restrict__ out) {
    extern __shared__ uint16_t lds[];
    int tid = threadIdx.x;
    int w = tid >> 6, l = tid & 63;
    int l15 = l & 15, l4 = l >> 4;
    int wr = w >> 2, wc = w & 3;
    int bid = blockIdx.x;
    int mt = (bid & 7) * 4 + ((bid >> 3) & 3);   // XCD-chunked M
    int nt = bid >> 5;                            // B-panel index
    int m0 = mt * 256, n0 = nt * 128;

    int r0 = tid >> 3, sl0 = tid & 7;
    int kc = sl0 ^ (r0 & 7);
    const uint16_t* pA = A + (size_t)(m0 + r0) * 1024 + kc * 8;
    const uint16_t* pB = BT + (size_t)(n0 + r0) * 1024 + kc * 8;
    int wofs = w * 512;

    f32x4 acc[8][2] = {};

    auto stageA = [&](int ks, int abA) {
#pragma unroll
        for (int q = 0; q < 4; ++q)
            gload16(pA + q * 65536 + ks * 64, lds + abA + q * 4096 + wofs);
    };
    auto stageB = [&](int ks, int abB) {
#pragma unroll
        for (int li = 0; li < 2; ++li)
            gload16(pB + li * 65536 + ks * 64, lds + abB + li * 4096 + wofs);
    };

    auto computeHalf = [&](int abA, int abB, int kk) {
        const uint16_t* Ah = lds + abA + wr * 8192;
        const uint16_t* Bb = lds + abB;
        int ch = ((kk * 4 + l4) ^ (l15 & 7)) * 8;
        bf16x8 af[8], bf[2];
#pragma unroll
        for (int fi = 0; fi < 8; ++fi)
            af[fi] = ld8(Ah + (fi * 16 + l15) * 64 + ch);
#pragma unroll
        for (int fj = 0; fj < 2; ++fj)
            bf[fj] = ld8(Bb + (wc * 32 + fj * 16 + l15) * 64 + ch);
        __builtin_amdgcn_s_setprio(1);
#pragma unroll
        for (int fi = 0; fi < 8; ++fi)
#pragma unroll
            for (int fj = 0; fj < 2; ++fj)
                acc[fi][fj] = __builtin_amdgcn_mfma_f32_16x16x32_bf16(
                    af[fi], bf[fj], acc[fi][fj], 0, 0, 0);
        __builtin_amdgcn_s_setprio(0);
    };

    auto step = [&](int s, int abA, int abB, int abAn, int abBn) {
        bool pf = (s + 1 < 16);
        if (pf) stageA(s + 1, abAn);
        computeHalf(abA, abB, 0);
        if (pf) stageB(s + 1, abBn);
        computeHalf(abA, abB, 1);
        asm volatile("s_waitcnt vmcnt(0)\n\ts_barrier" ::: "memory");
    };

    stageA(0, 0); stageB(0, 32768);
    asm volatile("s_waitcnt vmcnt(0)\n\ts_barrier" ::: "memory");
    for (int s = 0; s < 16; s += 2) {
        step(s,     0,     32768, 16384, 40960);
        step(s + 1, 16384, 40960, 0,     32768);
    }

    if constexpr (MODE == 0) {
        int b = m0 >> 11, nbase = m0 & 2047;
        if (n0 >= 2048) {
#pragma unroll
            for (int fi = 0; fi < 8; ++fi)
#pragma unroll
                for (int fj = 0; fj < 2; ++fj) {
                    int dl = wc * 32 + fj * 16 + l15;
                    int ml = wr * 128 + fi * 16 + l4 * 4;
                    union { uint16_t u[4]; uint2 v2; } pk;
#pragma unroll
                    for (int r = 0; r < 4; ++r) pk.u[r] = f2bf(acc[fi][fj][r]);
                    *(uint2*)&lds[dl * 264 + ml] = pk.v2;
                }
        __syncthreads();
#pragma unroll
            for (int it = 0; it < 8; ++it) {
                int idx = it * 512 + tid;
                int row = idx >> 5, col = (idx & 31) * 8;
                u32x4 val = *(u32x4*)&lds[row * 264 + col];
                int dv = (n0 - 2048) + row;
                int h = dv >> 6, dh = dv & 63;
                *(u32x4*)(vo + ((size_t)(b * 16 + h) * 64 + dh) * 2048 + nbase + col) = val;
            }
        } else {
            float sc = (n0 < 1024) ? 0.18033688011112042f : 1.0f;
            uint16_t* dst0 = (n0 < 1024) ? qo : ko;
#pragma unroll
            for (int fi = 0; fi < 8; ++fi)
#pragma unroll
                for (int fj = 0; fj < 2; ++fj) {
                    int d = n0 + wc * 32 + fj * 16 + l15;
                    int h = (d >> 6) & 15, dh = d & 63;
#pragma unroll
                    for (int r = 0; r < 4; ++r) {
                        int n = nbase + wr * 128 + fi * 16 + l4 * 4 + r;
                        dst0[((size_t)(b * 16 + h) * 2048 + n) * 64 + dh] = f2bf(acc[fi][fj][r] * sc);
                    }
                }
        }
    } else {
#pragma unroll
        for (int fj = 0; fj < 2; ++fj) {
            int d = n0 + wc * 32 + fj * 16 + l15;
            float bv = bias[d];
#pragma unroll
            for (int fi = 0; fi < 8; ++fi)
#pragma unroll
                for (int r = 0; r < 4; ++r) {
                    int m = m0 + wr * 128 + fi * 16 + l4 * 4 + r;
                    out[(size_t)m * 1024 + d] = acc[fi][fj][r] + bv;
                }
        }
    }
}

// ---------------- flash attention (no-max softmax, exp2 domain, KVBLK=128) ----------------
// R18-proven body EXACT (101.1 us): 4-wave blocks, doubled KV tile (128 keys),
// double-buffered K AND V (64KB LDS), split-barrier counted-vmcnt:
//   body t: vmcnt(4)+bar [K(t) ready; V(t) 4 in flight] -> stage(t+1): 8 loads,
//   K first then V -> QK(4 j-groups)+exp -> vmcnt(8)+bar [V(t) ready; t+1's 8
//   in flight] -> PV (8 kv-slots). Tail t=15: vmcnt(0).
// (R19's single-buffered-V variant: VGPR 128->140, occupancy 19.7->11%,
// attn 101->145us. V double-buffering IS the latency cover. FROZEN at R18.)
__global__ __launch_bounds__(256) void k_attn(
    const uint16_t* __restrict__ q, const uint16_t* __restrict__ kk_,
    const uint16_t* __restrict__ vt, uint16_t* __restrict__ o) {
    __shared__ uint16_t k_lds[2][128 * 64];
    __shared__ uint16_t v_lds[2][64 * 128];
    int tid = threadIdx.x;
    int w = tid >> 6, l = tid & 63;
    int l31 = l & 31, g = l >> 5;
    int bid = blockIdx.x;
    int slot = bid >> 3;
    int bh = (bid & 7) * 8 + (slot >> 4);
    int qt = slot & 15;
    int qrow = qt * 128 + w * 32 + l31;
    const uint16_t* qb = q + ((size_t)bh * 2048 + qrow) * 64;
    const uint16_t* kbase = kk_ + (size_t)bh * 2048 * 64;
    const uint16_t* vbase = vt + (size_t)bh * 64 * 2048;

    bf16x8 qf[4];
#pragma unroll
    for (int kv = 0; kv < 4; ++kv) qf[kv] = ld8(qb + kv * 16 + g * 8);

    // K staging: thread covers chunks c0+{0,64,128,192} (rows rrK+{0,8,16,24},
    // same slot; (rrK+8i)&7 == rrK&7 so one swizzled base + imm offsets works)
    int c0 = w * 256 + l;
    int rrK = c0 >> 3, slK = c0 & 7;
    int kcK = slK ^ (rrK & 7);
    const uint16_t* kp = kbase + (size_t)rrK * 64 + kcK * 8;
    // V^T staging: load i covers row rv0+4i, slot l&15 (XOR low-3 swizzle)
    int rv0 = w * 16 + (l >> 4);
    int sv = l & 15;
    const uint16_t* vpp0 = vbase + (size_t)(rv0 + 0)  * 2048 + (sv ^ ((rv0 + 0)  & 7)) * 8;
    const uint16_t* vpp1 = vbase + (size_t)(rv0 + 4)  * 2048 + (sv ^ ((rv0 + 4)  & 7)) * 8;
    const uint16_t* vpp2 = vbase + (size_t)(rv0 + 8)  * 2048 + (sv ^ ((rv0 + 8)  & 7)) * 8;
    const uint16_t* vpp3 = vbase + (size_t)(rv0 + 12) * 2048 + (sv ^ ((rv0 + 12) & 7)) * 8;
    uint16_t* kd0 = k_lds[0] + w * 2048;
    uint16_t* kd1 = k_lds[1] + w * 2048;
    uint16_t* vd0 = v_lds[0] + w * 2048;
    uint16_t* vd1 = v_lds[1] + w * 2048;

    f32x16 oa[2] = {};
    float lsum = 0.f;

    auto stage = [&](uint16_t* kd, uint16_t* vd) {
        gload16(kp,        kd);        gload16(kp + 512,  kd + 512);   // K first,
        gload16(kp + 1024, kd + 1024); gload16(kp + 1536, kd + 1536);
        gload16(vpp0, vd);        gload16(vpp1, vd + 512);             // V second
        gload16(vpp2, vd + 1024); gload16(vpp3, vd + 1536);
        kp += 8192;
        vpp0 += 128; vpp1 += 128; vpp2 += 128; vpp3 += 128;
    };

    stage(kd0, vd0);   // tile 0 -> buf 0  (8 outstanding)

    auto body = [&](int t, const uint16_t* kb, const uint16_t* vb,
                    uint16_t* kdn, uint16_t* vdn) {
        // K(t) ready for all waves (V(t)'s 4 still in flight)
        asm volatile("s_waitcnt vmcnt(4)\n\ts_barrier" ::: "memory");
        if (t < 15) stage(kdn, vdn);   // issue next tile ASAP

        // S^T = K * Q^T, P = exp2(S) in-register (4 x 32-key groups)
        bf16x8 pfrag[8];
#pragma unroll
        for (int j = 0; j < 4; ++j) {
            int key = j * 32 + l31;
            f32x16 stj = {};
            __builtin_amdgcn_s_setprio(1);
#pragma unroll
            for (int kv = 0; kv < 4; ++kv) {
                bf16x8 kf = ld8(kb + key * 64 + ((2 * kv + g) ^ (key & 7)) * 8);
                stj = __builtin_amdgcn_mfma_f32_32x32x16_bf16(kf, qf[kv], stj, 0, 0, 0);
            }
            __builtin_amdgcn_s_setprio(0);
#pragma unroll
            for (int h = 0; h < 2; ++h) {
                float e[8];
#pragma unroll
                for (int jj = 0; jj < 8; ++jj) e[jj] = exp2_fast(stj[h * 8 + jj]);
                lsum += ((e[0] + e[1]) + (e[2] + e[3])) + ((e[4] + e[5]) + (e[6] + e[7]));
                uint32_t a0 = cvtpk(e[0], e[1]), a1 = cvtpk(e[2], e[3]);
                uint32_t b0 = cvtpk(e[4], e[5]), b1 = cvtpk(e[6], e[7]);
                auto r0 = __builtin_amdgcn_permlane32_swap(a0, b0, false, false);
                auto r1 = __builtin_amdgcn_permlane32_swap(a1, b1, false, false);
                u32x4 f;
                f[0] = r0[0]; f[1] = r1[0]; f[2] = r0[1]; f[3] = r1[1];
                pfrag[j * 2 + h] = __builtin_bit_cast(bf16x8, f);
            }
        }

        // V(t) ready (t+1's 8 loads in flight)
        if (t < 15) asm volatile("s_waitcnt vmcnt(8)\n\ts_barrier" ::: "memory");
        else        asm volatile("s_waitcnt vmcnt(0)\n\ts_barrier" ::: "memory");

        // O^T += V^T * P^T  (8 x 16-key slots)
        __builtin_amdgcn_s_setprio(1);
#pragma unroll
        for (int kv = 0; kv < 8; ++kv) {
#pragma unroll
            for (int dt = 0; dt < 2; ++dt) {
                int dh = dt * 32 + l31;
                bf16x8 vf = ld8(vb + dh * 128 + ((2 * kv + g) ^ (dh & 7)) * 8);
                oa[dt] = __builtin_amdgcn_mfma_f32_32x32x16_bf16(vf, pfrag[kv], oa[dt], 0, 0, 0);
            }
        }
        __builtin_amdgcn_s_setprio(0);
    };

    for (int kt = 0; kt < 16; kt += 2) {
        body(kt,     k_lds[0], v_lds[0], kd1, vd1);
        body(kt + 1, k_lds[1], v_lds[1], kd0, vd0);
    }

    float ltot = lsum + __shfl_xor(lsum, 32, 64);
    float inv = 1.0f / ltot;
    int b = bh >> 4, h = bh & 15;
    uint16_t* ob = o + ((size_t)(b * 2048 + qrow)) * 1024 + h * 64;
#pragma unroll
    for (int dt = 0; dt < 2; ++dt)
#pragma unroll
        for (int rq = 0; rq < 4; ++rq) {
            union { uint16_t u[4]; uint2 v; } pk;
#pragma unroll
            for (int rr = 0; rr < 4; ++rr) pk.u[rr] = f2bf(oa[dt][rq * 4 + rr] * inv);
            int dh0 = dt * 32 + rq * 8 + g * 4;
            *(uint2*)(ob + dh0) = pk.v;
        }
}

extern "C" void kernel_launch(void* const* d_in, const int* in_sizes, int n_in,
                              void* d_out, int out_size, void* d_ws, size_t ws_size,
                              hipStream_t stream) {
    const float* x     = (const float*)d_in[0];
    // d_in[1] = xpos : unused by the reference
    const float* Wqkv  = (const float*)d_in[2];
    const float* Wproj = (const float*)d_in[3];
    const float* bproj = (const float*)d_in[4];
    float* out = (float*)d_out;

    char* ws = (char*)d_ws;
    uint16_t* xb     = (uint16_t*)(ws);                         // 16.78 MB
    uint16_t* wqkvT  = (uint16_t*)(ws + 16777216);              //  6.29 MB
    uint16_t* wprojT = (uint16_t*)(ws + 23068672);              //  2.10 MB
    uint16_t* qws    = (uint16_t*)(ws + 25165824);              // 16.78 MB
    uint16_t* kws    = (uint16_t*)(ws + 41943040);              // 16.78 MB
    uint16_t* vT     = (uint16_t*)(ws + 58720256);              // 16.78 MB (total ~75.5 MB)
    uint16_t* attnout = xb;  // xb is dead after QKV GEMM

    k_prep<<<dim3(5120), dim3(256), 0, stream>>>(x, xb, Wqkv, wqkvT, Wproj, wprojT);
    k_gemm<0><<<dim3(768), dim3(512), 98304, stream>>>(xb, wqkvT, nullptr, qws, kws, vT, nullptr);
    k_attn<<<dim3(1024), dim3(256), 0, stream>>>(qws, kws, vT, attnout);
    k_gemm<1><<<dim3(256), dim3(512), 98304, stream>>>(attnout, wprojT, bproj, nullptr, nullptr, nullptr, out);
}